// Round 12
// baseline (151.761 us; speedup 1.0000x reference)
//
#include <hip/hip_runtime.h>
#include <hip/hip_bf16.h>
#include <stdint.h>

#define N_ROWS 8192
#define DIM    2048
#define OUTD   2048
#define NEXP   8
#define RNK    16
#define ZCOLS  128          // NEXP*RNK
#define KAUG   2176         // DIM + ZCOLS

typedef unsigned short u16;
typedef float  f32x4  __attribute__((ext_vector_type(4)));
typedef __bf16 bf16x8 __attribute__((ext_vector_type(8)));

__device__ __forceinline__ u16 f2bf(float f) {
  unsigned u = __float_as_uint(f);
  return (u16)((u + 0x7fffu + ((u >> 16) & 1u)) >> 16);   // RNE
}

__device__ __forceinline__ bf16x8 cvt8(float4 a, float4 b) {
  union { u16 u[8]; bf16x8 v; } r;
  r.u[0] = f2bf(a.x); r.u[1] = f2bf(a.y); r.u[2] = f2bf(a.z); r.u[3] = f2bf(a.w);
  r.u[4] = f2bf(b.x); r.u[5] = f2bf(b.y); r.u[6] = f2bf(b.z); r.u[7] = f2bf(b.w);
  return r.v;
}

#define GLOAD(SRC, DST) __builtin_amdgcn_global_load_lds( \
    (__attribute__((address_space(1))) void*)(SRC), \
    (__attribute__((address_space(3))) void*)(DST), 16, 0, 0)

// ---- K2a: Ab = bf16(lora_A flat) — gates KF ----
__global__ __launch_bounds__(256) void k2a_lora(
    const float* __restrict__ lA, u16* __restrict__ ab)
{
  const int t  = threadIdx.x;
  const int ar = blockIdx.x;                // 0..127
  const float* src = lA + (size_t)ar * DIM;
  u16* dst = ab + (size_t)ar * DIM;
  #pragma unroll
  for (int i = 0; i < 2; ++i) {
    int c = t * 4 + i * 1024;
    float4 v = *(const float4*)(src + c);
    ushort4 s; s.x = f2bf(v.x); s.y = f2bf(v.y); s.z = f2bf(v.z); s.w = f2bf(v.w);
    *(ushort4*)(dst + c) = s;
  }
}

// ---- KFW: blocks 0..511 = barrier-free KF (x->bf16 + fp32 gates + xA MFMA + z).
//           blocks 512..2559 = Waug row conversion (only read by K4).
// KF: no LDS in loop. Lane roles per chunk (64 cols):
//   write/gate: row wr=4*wave+l16, quad l15 (coalesced float4; also HBM-pulls chunk)
//   A-frag:     row l15, k = C0+ks*32+l16*8 (2 float4 per ks, f2bf in-reg; L1/L2 hits)
//   B-frag:     ab rows 32*wave+l15 (+16), same k (bf16x8 direct; ab L2-resident)
// Gates: wave owns rows 4w..4w+3 fully -> wave-local shfl reduce; 1 syncthreads.
__global__ __launch_bounds__(256) void kfw_fused(
    const float* __restrict__ x, const float* __restrict__ gw,
    const float* __restrict__ gb, const u16* __restrict__ ab,
    u16* __restrict__ xaug,
    const float* __restrict__ W, const float* __restrict__ lB,
    u16* __restrict__ waug)
{
  const int t = threadIdx.x;

  if (blockIdx.x >= 512) {                  // ---- waug branch ----
    const int o = blockIdx.x - 512;         // 0..2047
    const float* wr = W + (size_t)o * DIM;
    u16* dst = waug + (size_t)o * KAUG;
    #pragma unroll
    for (int i = 0; i < 2; ++i) {
      int c = t * 4 + i * 1024;
      float4 v = *(const float4*)(wr + c);
      ushort4 s; s.x = f2bf(v.x); s.y = f2bf(v.y); s.z = f2bf(v.z); s.w = f2bf(v.w);
      *(ushort4*)(dst + c) = s;
    }
    if (t < ZCOLS) {
      int e = t >> 4, r = t & 15;
      dst[DIM + t] = f2bf(lB[((size_t)e * OUTD + o) * RNK + r]);
    }
    return;
  }

  // ---- KF branch ----
  __shared__ float4 gates[16];               // per-row {g0,g1,e0,e1}

  const int wave = t >> 6;
  const int lane = t & 63;
  const int l15  = lane & 15;
  const int l16  = lane >> 4;
  const size_t row0 = (size_t)blockIdx.x * 16;

  const int wr = 4 * wave + l16;             // write/gate row (wave owns 4 rows)
  const float* xw = x  + (row0 + wr)  * DIM + l15 * 4;   // write/gate stream
  const float* xa = x  + (row0 + l15) * DIM + l16 * 8;   // A-frag stream
  const u16*   bA = ab + (size_t)(32 * wave + l15)      * DIM + l16 * 8;
  const u16*   bB = ab + (size_t)(32 * wave + 16 + l15) * DIM + l16 * 8;
  u16* xo = xaug + (row0 + wr) * KAUG + l15 * 4;

  float ga[NEXP] = {};
  f32x4 acc[2] = {};

  for (int c = 0; c < 32; ++c) {
    const int C0 = c * 64;
    // loads (no barriers; TLP hides latency)
    float4 wv = *(const float4*)(xw + C0);
    float4 af[2][2];
    #pragma unroll
    for (int ks = 0; ks < 2; ++ks) {
      af[ks][0] = *(const float4*)(xa + C0 + ks * 32);
      af[ks][1] = *(const float4*)(xa + C0 + ks * 32 + 4);
    }
    bf16x8 bva[2], bvb[2];
    #pragma unroll
    for (int ks = 0; ks < 2; ++ks) {
      bva[ks] = *(const bf16x8*)(bA + C0 + ks * 32);
      bvb[ks] = *(const bf16x8*)(bB + C0 + ks * 32);
    }
    float4 gv4[NEXP];
    #pragma unroll
    for (int e = 0; e < NEXP; ++e)
      gv4[e] = *(const float4*)(gw + (size_t)e * DIM + C0 + l15 * 4);

    // base xaug write (bf16 RNE)
    ushort4 s; s.x = f2bf(wv.x); s.y = f2bf(wv.y); s.z = f2bf(wv.z); s.w = f2bf(wv.w);
    *(ushort4*)(xo + C0) = s;
    // gate partials (fp32)
    #pragma unroll
    for (int e = 0; e < NEXP; ++e)
      ga[e] += wv.x * gv4[e].x + wv.y * gv4[e].y + wv.z * gv4[e].z + wv.w * gv4[e].w;
    // A-frag convert + MFMA
    #pragma unroll
    for (int ks = 0; ks < 2; ++ks) {
      bf16x8 av = cvt8(af[ks][0], af[ks][1]);
      acc[0] = __builtin_amdgcn_mfma_f32_16x16x32_bf16(av, bva[ks], acc[0], 0, 0, 0);
      acc[1] = __builtin_amdgcn_mfma_f32_16x16x32_bf16(av, bvb[ks], acc[1], 0, 0, 0);
    }
  }

  // gate reduce: lanes sharing row wr differ only in l15 -> xor 1,2,4,8
  #pragma unroll
  for (int e = 0; e < NEXP; ++e) {
    float v = ga[e];
    v += __shfl_xor(v, 1); v += __shfl_xor(v, 2);
    v += __shfl_xor(v, 4); v += __shfl_xor(v, 8);
    ga[e] = v + gb[e];
  }
  if (l15 == 0) {
    int e0 = 0; float m0 = ga[0];
    #pragma unroll
    for (int e = 1; e < NEXP; ++e) if (ga[e] > m0) { m0 = ga[e]; e0 = e; }
    int e1 = (e0 == 0) ? 1 : 0; float m1 = ga[e1];
    #pragma unroll
    for (int e = 0; e < NEXP; ++e) if (e != e0 && ga[e] > m1) { m1 = ga[e]; e1 = e; }
    float tt  = expf(m1 - m0);
    float inv = 1.f / (1.f + tt);
    float4 gg; gg.x = inv; gg.y = tt * inv;
    gg.z = __int_as_float(e0); gg.w = __int_as_float(e1);
    gates[wr] = gg;
  }
  __syncthreads();

  // gated z write: wave covers experts 2w, 2w+1; D row m = l16*4+j, col = l15
  #pragma unroll
  for (int nfl = 0; nfl < 2; ++nfl) {
    const int e = 2 * wave + nfl;
    const int n = e * 16 + l15;
    #pragma unroll
    for (int j = 0; j < 4; ++j) {
      const int m = l16 * 4 + j;
      float4 gg = gates[m];
      const float g = (e == __float_as_int(gg.z)) ? gg.x
                    : ((e == __float_as_int(gg.w)) ? gg.y : 0.f);
      xaug[(row0 + m) * KAUG + DIM + n] = f2bf(acc[nfl][j] * g);
    }
  }
}

// ---- K4: round-8 exact structure (best measured: 75.2 us).
// 256x256 tile, BK=64, 2-slot ring, counted vmcnt(8), 3-group MFMA interleave ----
__global__ __launch_bounds__(512, 2) void gemm256_pipe(
    const u16* __restrict__ A, int lda,
    const u16* __restrict__ Bm, int ldb,
    int Ksz, int grid_n,
    float* __restrict__ outF, int ldo, const float* __restrict__ bias)
{
  __shared__ __align__(16) u16 smem[65536];      // 128 KiB: A[2][32K] | B[2][32K]

  const int tid  = threadIdx.x;
  const int wave = tid >> 6;
  const int lane = tid & 63;

  int bid = blockIdx.x;
  const int nwg = gridDim.x;
  if ((nwg & 7) == 0) {                          // bijective XCD swizzle
    const int cpx = nwg >> 3;
    bid = (bid & 7) * cpx + (bid >> 3);
  }
  const int tm = bid / grid_n;
  const int tn = bid % grid_n;
  const size_t row0 = (size_t)tm * 256;
  const size_t col0 = (size_t)tn * 256;

  const int l3  = lane >> 3;
  const int sch = ((lane & 7) ^ l3) << 4;
  const char* aSrc = (const char*)(A  + (row0 + (size_t)(wave * 8 + l3)) * lda) + sch;
  const char* bSrc = (const char*)(Bm + (col0 + (size_t)(wave * 8 + l3)) * ldb) + sch;
  const size_t arst = (size_t)lda * 128;
  const size_t brst = (size_t)ldb * 128;
  char* ldsA = (char*)smem + wave * 1024;
  char* ldsB = (char*)smem + 65536 + wave * 1024;

  auto stage = [&](int tt) {
    const size_t ko = (size_t)tt * 128;
    const int    sb = (tt & 1) << 15;
    #pragma unroll
    for (int i = 0; i < 4; ++i)
      GLOAD(aSrc + ko + i * arst, ldsA + sb + i * 8192);
    #pragma unroll
    for (int i = 0; i < 4; ++i)
      GLOAD(bSrc + ko + i * brst, ldsB + sb + i * 8192);
  };

  const int wm = wave >> 2, wn = wave & 3;
  const int x0 = ((lane >> 4) ^ (lane & 7)) << 4;
  const int offA0 = wm * 16384 + (lane & 15) * 128 + x0;
  const int offB0 = wn * 8192  + (lane & 15) * 128 + x0;

  f32x4 acc[8][4] = {};

  const int nk = Ksz / 64;                        // 34
  stage(0); stage(1);

  for (int t = 0; t < nk; ++t) {
    if (t + 1 < nk) asm volatile("s_waitcnt vmcnt(8)" ::: "memory");
    else            asm volatile("s_waitcnt vmcnt(0)" ::: "memory");
    __builtin_amdgcn_s_barrier();
    __builtin_amdgcn_sched_barrier(0);

    const char* sa = (const char*)smem + ((t & 1) << 15);
    const char* sb = (const char*)smem + 65536 + ((t & 1) << 15);

    bf16x8 av0[8], bv0[4], av1[8], bv1[4];
    // ks0 reads
    #pragma unroll
    for (int mf = 0; mf < 8; ++mf) av0[mf] = *(const bf16x8*)(sa + offA0 + mf * 2048);
    #pragma unroll
    for (int nf = 0; nf < 4; ++nf) bv0[nf] = *(const bf16x8*)(sb + offB0 + nf * 2048);
    // group 1: ks0 x nf0-1 (16 MFMA)
    __builtin_amdgcn_s_setprio(1);
    #pragma unroll
    for (int mf = 0; mf < 8; ++mf)
      #pragma unroll
      for (int nf = 0; nf < 2; ++nf)
        acc[mf][nf] = __builtin_amdgcn_mfma_f32_16x16x32_bf16(
            av0[mf], bv0[nf], acc[mf][nf], 0, 0, 0);
    __builtin_amdgcn_s_setprio(0);
    // ks1 reads — issue overlaps group-2 MFMA
    #pragma unroll
    for (int mf = 0; mf < 8; ++mf) av1[mf] = *(const bf16x8*)(sa + (offA0 ^ 64) + mf * 2048);
    #pragma unroll
    for (int nf = 0; nf < 4; ++nf) bv1[nf] = *(const bf16x8*)(sb + (offB0 ^ 64) + nf * 2048);
    // group 2: ks0 x nf2-3 (16 MFMA)
    __builtin_amdgcn_s_setprio(1);
    #pragma unroll
    for (int mf = 0; mf < 8; ++mf)
      #pragma unroll
      for (int nf = 2; nf < 4; ++nf)
        acc[mf][nf] = __builtin_amdgcn_mfma_f32_16x16x32_bf16(
            av0[mf], bv0[nf], acc[mf][nf], 0, 0, 0);
    __builtin_amdgcn_s_setprio(0);
    // slot free after all reads complete in every wave
    asm volatile("s_waitcnt lgkmcnt(0)" ::: "memory");
    __builtin_amdgcn_s_barrier();
    __builtin_amdgcn_sched_barrier(0);
    if (t + 2 < nk) stage(t + 2);
    // group 3: ks1 x all nf (32 MFMA) — covers staging
    __builtin_amdgcn_s_setprio(1);
    #pragma unroll
    for (int mf = 0; mf < 8; ++mf)
      #pragma unroll
      for (int nf = 0; nf < 4; ++nf)
        acc[mf][nf] = __builtin_amdgcn_mfma_f32_16x16x32_bf16(
            av1[mf], bv1[nf], acc[mf][nf], 0, 0, 0);
    __builtin_amdgcn_s_setprio(0);
  }

  #pragma unroll
  for (int nf = 0; nf < 4; ++nf) {
    const size_t c = col0 + wn * 64 + nf * 16 + (lane & 15);
    const float bvv = bias[c];
    #pragma unroll
    for (int mf = 0; mf < 8; ++mf) {
      const size_t rb = row0 + wm * 128 + mf * 16 + ((lane >> 4) << 2);
      #pragma unroll
      for (int j = 0; j < 4; ++j)
        outF[(rb + j) * (size_t)ldo + c] = acc[mf][nf][j] + bvv;
    }
  }
}

extern "C" void kernel_launch(void* const* d_in, const int* in_sizes, int n_in,
                              void* d_out, int out_size, void* d_ws, size_t ws_size,
                              hipStream_t stream) {
  const float* x  = (const float*)d_in[0];
  const float* W  = (const float*)d_in[1];
  const float* b  = (const float*)d_in[2];
  const float* lA = (const float*)d_in[3];
  const float* lB = (const float*)d_in[4];
  const float* gw = (const float*)d_in[5];
  const float* gb = (const float*)d_in[6];
  float* out = (float*)d_out;

  u16* xaug = (u16*)d_ws;                          // [8192][2176]
  u16* waug = xaug + (size_t)N_ROWS * KAUG;        // [2048][2176]
  u16* ab   = waug + (size_t)OUTD * KAUG;          // [128][2048]

  hipLaunchKernelGGL(k2a_lora, dim3(ZCOLS), dim3(256), 0, stream, lA, ab);
  hipLaunchKernelGGL(kfw_fused, dim3(512 + OUTD), dim3(256), 0, stream,
                     x, gw, gb, ab, xaug, W, lB, waug);
  hipLaunchKernelGGL(gemm256_pipe,
                     dim3((N_ROWS / 256) * (OUTD / 256)), dim3(512), 0, stream,
                     xaug, KAUG, waug, KAUG, KAUG, OUTD / 256,
                     out, OUTD, b);
}

// Round 13
// 137.863 us; speedup vs baseline: 1.1008x; 1.1008x over previous
//
#include <hip/hip_runtime.h>
#include <hip/hip_bf16.h>
#include <stdint.h>

#define N_ROWS 8192
#define DIM    2048
#define OUTD   2048
#define NEXP   8
#define RNK    16
#define ZCOLS  128          // NEXP*RNK
#define KAUG   2176         // DIM + ZCOLS
#define KFB    1024         // KF blocks (8 rows each)

typedef unsigned short u16;
typedef float  f32x4  __attribute__((ext_vector_type(4)));
typedef __bf16 bf16x8 __attribute__((ext_vector_type(8)));

__device__ __forceinline__ u16 f2bf(float f) {
  unsigned u = __float_as_uint(f);
  return (u16)((u + 0x7fffu + ((u >> 16) & 1u)) >> 16);   // RNE
}

#define GLOAD(SRC, DST) __builtin_amdgcn_global_load_lds( \
    (__attribute__((address_space(1))) void*)(SRC), \
    (__attribute__((address_space(3))) void*)(DST), 16, 0, 0)

// ---- K2a: Ab = bf16(lora_A flat) — gates KF ----
__global__ __launch_bounds__(256) void k2a_lora(
    const float* __restrict__ lA, u16* __restrict__ ab)
{
  const int t  = threadIdx.x;
  const int ar = blockIdx.x;                // 0..127
  const float* src = lA + (size_t)ar * DIM;
  u16* dst = ab + (size_t)ar * DIM;
  #pragma unroll
  for (int i = 0; i < 2; ++i) {
    int c = t * 4 + i * 1024;
    float4 v = *(const float4*)(src + c);
    ushort4 s; s.x = f2bf(v.x); s.y = f2bf(v.y); s.z = f2bf(v.z); s.w = f2bf(v.w);
    *(ushort4*)(dst + c) = s;
  }
}

// ---- KFW: blocks 0..1023 = KF (8 rows each; 4 blocks/CU for latency hiding).
//           blocks 1024..3071 = Waug row conversion (only read by K4). ----
// KF: R8 discipline (la gload_lds dbuf, vmcnt(22)+lgkm0, 2 barriers/chunk).
// Thread roles: row r=t>>5 (0..7), col-pair q=t&31 (float2). xb rows 8-15
// garbage (D[m] only uses A-row m -> discarded rows can't pollute rows <8).
__global__ __launch_bounds__(256) void kfw_fused(
    const float* __restrict__ x, const float* __restrict__ gw,
    const float* __restrict__ gb, const u16* __restrict__ ab,
    u16* __restrict__ xaug,
    const float* __restrict__ W, const float* __restrict__ lB,
    u16* __restrict__ waug)
{
  const int t = threadIdx.x;

  if (blockIdx.x >= KFB) {                  // ---- waug branch ----
    const int o = blockIdx.x - KFB;         // 0..2047
    const float* wr = W + (size_t)o * DIM;
    u16* dst = waug + (size_t)o * KAUG;
    #pragma unroll
    for (int i = 0; i < 2; ++i) {
      int c = t * 4 + i * 1024;
      float4 v = *(const float4*)(wr + c);
      ushort4 s; s.x = f2bf(v.x); s.y = f2bf(v.y); s.z = f2bf(v.z); s.w = f2bf(v.w);
      *(ushort4*)(dst + c) = s;
    }
    if (t < ZCOLS) {
      int e = t >> 4, r = t & 15;
      dst[DIM + t] = f2bf(lB[((size_t)e * OUTD + o) * RNK + r]);
    }
    return;
  }

  // ---- KF branch ----
  __shared__ __align__(16) u16 la[2][8192];  // 2 x [128][64] bf16, swizzled (32 KB)
  __shared__ __align__(16) u16 xb[1024];     // [16][64] bf16 (rows 8-15 unused)
  __shared__ float4 gates[8];                // per-row {g0,g1,e0,e1}

  const int wave = t >> 6;
  const int lane = t & 63;
  const int r    = t >> 5;                   // 0..7
  const int q    = t & 31;                   // col pair (2 cols)
  const size_t row0 = (size_t)blockIdx.x * 8;

  int lrow[4], lsch[4];
  #pragma unroll
  for (int i = 0; i < 4; ++i) {
    const int g = t + i * 256;               // chunk id 0..1023
    lrow[i] = g >> 3;
    lsch[i] = (g & 7) ^ (lrow[i] & 7);
  }

  auto stage_la = [&](int c, int h) {
    const int C0 = c * 64;
    #pragma unroll
    for (int i = 0; i < 4; ++i) {
      const char* src = (const char*)(ab + (size_t)lrow[i] * DIM + C0 + lsch[i] * 8);
      GLOAD(src, (char*)la[h] + (wave * 64 + i * 256) * 16);
    }
  };

  // stage FIRST so the vmcnt(22) count holds at c=0
  stage_la(0, 0);
  __builtin_amdgcn_sched_barrier(0);

  float2 xv, gwv[8];
  xv = *(const float2*)(x + (row0 + r) * DIM + q * 2);
  #pragma unroll
  for (int e = 0; e < NEXP; ++e)
    gwv[e] = *(const float2*)(gw + (size_t)e * DIM + q * 2);

  float ga[NEXP] = {};
  f32x4 acc[2] = {};
  const int nfA = 2 * wave, nfB = 2 * wave + 1;

  for (int c = 0; c < 32; ++c) {
    const int C0 = c * 64;
    if (c + 1 < 32) stage_la(c + 1, (c + 1) & 1);
    __builtin_amdgcn_sched_barrier(0);
    float2 xvn, gwvn[8];
    if (c + 1 < 32) {
      xvn = *(const float2*)(x + (row0 + r) * DIM + C0 + 64 + q * 2);
      #pragma unroll
      for (int e = 0; e < NEXP; ++e)
        gwvn[e] = *(const float2*)(gw + (size_t)e * DIM + C0 + 64 + q * 2);
    }
    __builtin_amdgcn_sched_barrier(0);
    // compute with current xv: base write, gate FMA, xb write
    ushort2 s; s.x = f2bf(xv.x); s.y = f2bf(xv.y);
    *(ushort2*)(xaug + (row0 + r) * KAUG + C0 + q * 2) = s;
    #pragma unroll
    for (int e = 0; e < NEXP; ++e)
      ga[e] += xv.x * gwv[e].x + xv.y * gwv[e].y;
    // xb: row r, cols 2q..2q+1 -> chunk ch=q>>2 (swizzled), byte (q&3)*4
    *(ushort2*)((char*)xb + r * 128 + (((q >> 2) ^ (r & 7)) * 16) + (q & 3) * 4) = s;

    if (c + 1 < 32) asm volatile("s_waitcnt vmcnt(22) lgkmcnt(0)" ::: "memory");
    else            asm volatile("s_waitcnt vmcnt(0) lgkmcnt(0)" ::: "memory");
    __builtin_amdgcn_sched_barrier(0);
    __builtin_amdgcn_s_barrier();

    const char* laP = (const char*)la[c & 1];
    #pragma unroll
    for (int ks = 0; ks < 2; ++ks) {
      const int ra = lane & 15;
      const int pa = ((ks * 4 + (lane >> 4)) ^ (ra & 7)) * 16;
      bf16x8 avf = *(const bf16x8*)((char*)xb + ra * 128 + pa);
      const int rbA = (lane & 15) + 16 * nfA;
      const int rbB = (lane & 15) + 16 * nfB;
      bf16x8 bvA = *(const bf16x8*)(laP + rbA * 128 + (((ks * 4 + (lane >> 4)) ^ (rbA & 7)) * 16));
      bf16x8 bvB = *(const bf16x8*)(laP + rbB * 128 + (((ks * 4 + (lane >> 4)) ^ (rbB & 7)) * 16));
      acc[0] = __builtin_amdgcn_mfma_f32_16x16x32_bf16(avf, bvA, acc[0], 0, 0, 0);
      acc[1] = __builtin_amdgcn_mfma_f32_16x16x32_bf16(avf, bvB, acc[1], 0, 0, 0);
    }
    __builtin_amdgcn_s_barrier();
    __builtin_amdgcn_sched_barrier(0);
    xv = xvn;
    #pragma unroll
    for (int e = 0; e < NEXP; ++e) gwv[e] = gwvn[e];
  }

  // gate reduce: lanes sharing row r = xor over bits 0..4 (32-lane group)
  #pragma unroll
  for (int e = 0; e < NEXP; ++e) {
    float v = ga[e];
    v += __shfl_xor(v, 1); v += __shfl_xor(v, 2);
    v += __shfl_xor(v, 4); v += __shfl_xor(v, 8);
    v += __shfl_xor(v, 16);
    ga[e] = v + gb[e];
  }
  if (q == 0) {
    int e0 = 0; float m0 = ga[0];
    #pragma unroll
    for (int e = 1; e < NEXP; ++e) if (ga[e] > m0) { m0 = ga[e]; e0 = e; }
    int e1 = (e0 == 0) ? 1 : 0; float m1 = ga[e1];
    #pragma unroll
    for (int e = 0; e < NEXP; ++e) if (e != e0 && ga[e] > m1) { m1 = ga[e]; e1 = e; }
    float tt  = expf(m1 - m0);
    float inv = 1.f / (1.f + tt);
    float4 gg; gg.x = inv; gg.y = tt * inv;
    gg.z = __int_as_float(e0); gg.w = __int_as_float(e1);
    gates[r] = gg;
  }
  __syncthreads();

  // gated z write: wave covers experts 2w,2w+1; D row m=(lane>>4)*4+j (keep m<8)
  #pragma unroll
  for (int nfl = 0; nfl < 2; ++nfl) {
    const int e = 2 * wave + nfl;
    const int n = e * 16 + (lane & 15);
    #pragma unroll
    for (int j = 0; j < 4; ++j) {
      const int m = (lane >> 4) * 4 + j;
      if (m < 8) {
        float4 gg = gates[m];
        const float g = (e == __float_as_int(gg.z)) ? gg.x
                      : ((e == __float_as_int(gg.w)) ? gg.y : 0.f);
        xaug[(row0 + m) * KAUG + DIM + n] = f2bf(acc[nfl][j] * g);
      }
    }
  }
}

// ---- K4: round-8 exact structure (best measured: 75.2 us).
// 256x256 tile, BK=64, 2-slot ring, counted vmcnt(8), 3-group MFMA interleave ----
__global__ __launch_bounds__(512, 2) void gemm256_pipe(
    const u16* __restrict__ A, int lda,
    const u16* __restrict__ Bm, int ldb,
    int Ksz, int grid_n,
    float* __restrict__ outF, int ldo, const float* __restrict__ bias)
{
  __shared__ __align__(16) u16 smem[65536];      // 128 KiB: A[2][32K] | B[2][32K]

  const int tid  = threadIdx.x;
  const int wave = tid >> 6;
  const int lane = tid & 63;

  int bid = blockIdx.x;
  const int nwg = gridDim.x;
  if ((nwg & 7) == 0) {                          // bijective XCD swizzle
    const int cpx = nwg >> 3;
    bid = (bid & 7) * cpx + (bid >> 3);
  }
  const int tm = bid / grid_n;
  const int tn = bid % grid_n;
  const size_t row0 = (size_t)tm * 256;
  const size_t col0 = (size_t)tn * 256;

  const int l3  = lane >> 3;
  const int sch = ((lane & 7) ^ l3) << 4;
  const char* aSrc = (const char*)(A  + (row0 + (size_t)(wave * 8 + l3)) * lda) + sch;
  const char* bSrc = (const char*)(Bm + (col0 + (size_t)(wave * 8 + l3)) * ldb) + sch;
  const size_t arst = (size_t)lda * 128;
  const size_t brst = (size_t)ldb * 128;
  char* ldsA = (char*)smem + wave * 1024;
  char* ldsB = (char*)smem + 65536 + wave * 1024;

  auto stage = [&](int tt) {
    const size_t ko = (size_t)tt * 128;
    const int    sb = (tt & 1) << 15;
    #pragma unroll
    for (int i = 0; i < 4; ++i)
      GLOAD(aSrc + ko + i * arst, ldsA + sb + i * 8192);
    #pragma unroll
    for (int i = 0; i < 4; ++i)
      GLOAD(bSrc + ko + i * brst, ldsB + sb + i * 8192);
  };

  const int wm = wave >> 2, wn = wave & 3;
  const int x0 = ((lane >> 4) ^ (lane & 7)) << 4;
  const int offA0 = wm * 16384 + (lane & 15) * 128 + x0;
  const int offB0 = wn * 8192  + (lane & 15) * 128 + x0;

  f32x4 acc[8][4] = {};

  const int nk = Ksz / 64;                        // 34
  stage(0); stage(1);

  for (int t = 0; t < nk; ++t) {
    if (t + 1 < nk) asm volatile("s_waitcnt vmcnt(8)" ::: "memory");
    else            asm volatile("s_waitcnt vmcnt(0)" ::: "memory");
    __builtin_amdgcn_s_barrier();
    __builtin_amdgcn_sched_barrier(0);

    const char* sa = (const char*)smem + ((t & 1) << 15);
    const char* sb = (const char*)smem + 65536 + ((t & 1) << 15);

    bf16x8 av0[8], bv0[4], av1[8], bv1[4];
    // ks0 reads
    #pragma unroll
    for (int mf = 0; mf < 8; ++mf) av0[mf] = *(const bf16x8*)(sa + offA0 + mf * 2048);
    #pragma unroll
    for (int nf = 0; nf < 4; ++nf) bv0[nf] = *(const bf16x8*)(sb + offB0 + nf * 2048);
    // group 1: ks0 x nf0-1 (16 MFMA)
    __builtin_amdgcn_s_setprio(1);
    #pragma unroll
    for (int mf = 0; mf < 8; ++mf)
      #pragma unroll
      for (int nf = 0; nf < 2; ++nf)
        acc[mf][nf] = __builtin_amdgcn_mfma_f32_16x16x32_bf16(
            av0[mf], bv0[nf], acc[mf][nf], 0, 0, 0);
    __builtin_amdgcn_s_setprio(0);
    // ks1 reads — issue overlaps group-2 MFMA
    #pragma unroll
    for (int mf = 0; mf < 8; ++mf) av1[mf] = *(const bf16x8*)(sa + (offA0 ^ 64) + mf * 2048);
    #pragma unroll
    for (int nf = 0; nf < 4; ++nf) bv1[nf] = *(const bf16x8*)(sb + (offB0 ^ 64) + nf * 2048);
    // group 2: ks0 x nf2-3 (16 MFMA)
    __builtin_amdgcn_s_setprio(1);
    #pragma unroll
    for (int mf = 0; mf < 8; ++mf)
      #pragma unroll
      for (int nf = 2; nf < 4; ++nf)
        acc[mf][nf] = __builtin_amdgcn_mfma_f32_16x16x32_bf16(
            av0[mf], bv0[nf], acc[mf][nf], 0, 0, 0);
    __builtin_amdgcn_s_setprio(0);
    // slot free after all reads complete in every wave
    asm volatile("s_waitcnt lgkmcnt(0)" ::: "memory");
    __builtin_amdgcn_s_barrier();
    __builtin_amdgcn_sched_barrier(0);
    if (t + 2 < nk) stage(t + 2);
    // group 3: ks1 x all nf (32 MFMA) — covers staging
    __builtin_amdgcn_s_setprio(1);
    #pragma unroll
    for (int mf = 0; mf < 8; ++mf)
      #pragma unroll
      for (int nf = 0; nf < 4; ++nf)
        acc[mf][nf] = __builtin_amdgcn_mfma_f32_16x16x32_bf16(
            av1[mf], bv1[nf], acc[mf][nf], 0, 0, 0);
    __builtin_amdgcn_s_setprio(0);
  }

  #pragma unroll
  for (int nf = 0; nf < 4; ++nf) {
    const size_t c = col0 + wn * 64 + nf * 16 + (lane & 15);
    const float bvv = bias[c];
    #pragma unroll
    for (int mf = 0; mf < 8; ++mf) {
      const size_t rb = row0 + wm * 128 + mf * 16 + ((lane >> 4) << 2);
      #pragma unroll
      for (int j = 0; j < 4; ++j)
        outF[(rb + j) * (size_t)ldo + c] = acc[mf][nf][j] + bvv;
    }
  }
}

extern "C" void kernel_launch(void* const* d_in, const int* in_sizes, int n_in,
                              void* d_out, int out_size, void* d_ws, size_t ws_size,
                              hipStream_t stream) {
  const float* x  = (const float*)d_in[0];
  const float* W  = (const float*)d_in[1];
  const float* b  = (const float*)d_in[2];
  const float* lA = (const float*)d_in[3];
  const float* lB = (const float*)d_in[4];
  const float* gw = (const float*)d_in[5];
  const float* gb = (const float*)d_in[6];
  float* out = (float*)d_out;

  u16* xaug = (u16*)d_ws;                          // [8192][2176]
  u16* waug = xaug + (size_t)N_ROWS * KAUG;        // [2048][2176]
  u16* ab   = waug + (size_t)OUTD * KAUG;          // [128][2048]

  hipLaunchKernelGGL(k2a_lora, dim3(ZCOLS), dim3(256), 0, stream, lA, ab);
  hipLaunchKernelGGL(kfw_fused, dim3(KFB + OUTD), dim3(256), 0, stream,
                     x, gw, gb, ab, xaug, W, lB, waug);
  hipLaunchKernelGGL(gemm256_pipe,
                     dim3((N_ROWS / 256) * (OUTD / 256)), dim3(512), 0, stream,
                     xaug, KAUG, waug, KAUG, KAUG, OUTD / 256,
                     out, OUTD, b);
}

// Round 16
// 115.426 us; speedup vs baseline: 1.3148x; 1.1944x over previous
//
#include <hip/hip_runtime.h>
#include <hip/hip_bf16.h>
#include <stdint.h>

#define N_ROWS 8192
#define DIM    2048
#define OUTD   2048
#define NEXP   8
#define RNK    16
#define ZCOLS  128          // NEXP*RNK
#define KAUG   2176         // DIM + ZCOLS

typedef unsigned short u16;
typedef float  f32x4  __attribute__((ext_vector_type(4)));
typedef __bf16 bf16x8 __attribute__((ext_vector_type(8)));

__device__ __forceinline__ u16 f2bf(float f) {
  unsigned u = __float_as_uint(f);
  return (u16)((u + 0x7fffu + ((u >> 16) & 1u)) >> 16);   // RNE
}

#define GLOAD(SRC, DST) __builtin_amdgcn_global_load_lds( \
    (__attribute__((address_space(1))) void*)(SRC), \
    (__attribute__((address_space(3))) void*)(DST), 16, 0, 0)

// ---- K2a: Ab = bf16(lora_A flat) — only this part gates KF ----
__global__ __launch_bounds__(256) void k2a_lora(
    const float* __restrict__ lA, u16* __restrict__ ab)
{
  const int t  = threadIdx.x;
  const int ar = blockIdx.x;                // 0..127
  const float* src = lA + (size_t)ar * DIM;
  u16* dst = ab + (size_t)ar * DIM;
  #pragma unroll
  for (int i = 0; i < 2; ++i) {
    int c = t * 4 + i * 1024;
    float4 v = *(const float4*)(src + c);
    ushort4 s; s.x = f2bf(v.x); s.y = f2bf(v.y); s.z = f2bf(v.z); s.w = f2bf(v.w);
    *(ushort4*)(dst + c) = s;
  }
}

// ---- KFW: blocks 0..511 = fused x->bf16 + fp32 gates + xA MFMA + gated z.
//           blocks 512..2559 = Waug row conversion (only read by K4).
// SAFETY-MARGINED WAIT (r16): vmcnt(14) instead of 22. Allow-set = at most the
// current iteration's ops (stage 4 + prefetch 9 + store 1); la(c) is strictly
// older than all of them, so it is retired regardless of how the compiler
// counts stores or schedules loads. Zero-margin vmcnt(22) was the suspected
// stochastic replay race (R14/R15 post-timing divergence).
__global__ __launch_bounds__(256) void kfw_fused(
    const float* __restrict__ x, const float* __restrict__ gw,
    const float* __restrict__ gb, const u16* __restrict__ ab,
    u16* __restrict__ xaug,
    const float* __restrict__ W, const float* __restrict__ lB,
    u16* __restrict__ waug)
{
  const int t = threadIdx.x;

  if (blockIdx.x >= 512) {                  // ---- waug branch ----
    const int o = blockIdx.x - 512;         // 0..2047
    const float* wr = W + (size_t)o * DIM;
    u16* dst = waug + (size_t)o * KAUG;
    #pragma unroll
    for (int i = 0; i < 2; ++i) {
      int c = t * 4 + i * 1024;
      float4 v = *(const float4*)(wr + c);
      ushort4 s; s.x = f2bf(v.x); s.y = f2bf(v.y); s.z = f2bf(v.z); s.w = f2bf(v.w);
      *(ushort4*)(dst + c) = s;
    }
    if (t < ZCOLS) {
      int e = t >> 4, r = t & 15;
      dst[DIM + t] = f2bf(lB[((size_t)e * OUTD + o) * RNK + r]);
    }
    return;
  }

  // ---- KF branch ----
  __shared__ __align__(16) u16 la[2][8192];  // 2 x [128][64] bf16, swizzled
  __shared__ __align__(16) u16 xb[1024];     // [16][64] bf16, swizzled
  __shared__ float4 gates[16];               // per-row {g0,g1,e0,e1}

  const int wave = t >> 6;
  const int lane = t & 63;
  const int r    = t >> 4;                   // 0..15
  const int q    = t & 15;                   // col quad
  const size_t row0 = (size_t)blockIdx.x * 16;

  int   lrow[4], lsch[4];
  #pragma unroll
  for (int i = 0; i < 4; ++i) {
    const int g = t + i * 256;               // chunk id 0..1023
    lrow[i] = g >> 3;
    lsch[i] = (g & 7) ^ (lrow[i] & 7);
  }

  auto stage_la = [&](int c, int h) {
    const int C0 = c * 64;
    #pragma unroll
    for (int i = 0; i < 4; ++i) {
      const char* src = (const char*)(ab + (size_t)lrow[i] * DIM + C0 + lsch[i] * 8);
      GLOAD(src, (char*)la[h] + (wave * 64 + i * 256) * 16);
    }
  };

  stage_la(0, 0);
  __builtin_amdgcn_sched_barrier(0);

  float4 xv, gwv[8];
  xv = *(const float4*)(x + (row0 + r) * DIM + q * 4);
  #pragma unroll
  for (int e = 0; e < NEXP; ++e)
    gwv[e] = *(const float4*)(gw + (size_t)e * DIM + q * 4);

  float ga[NEXP] = {};
  f32x4 acc[2] = {};
  const int nfA = 2 * wave, nfB = 2 * wave + 1;

  for (int c = 0; c < 32; ++c) {
    const int C0 = c * 64;
    if (c + 1 < 32) stage_la(c + 1, (c + 1) & 1);
    __builtin_amdgcn_sched_barrier(0);
    float4 xvn, gwvn[8];
    if (c + 1 < 32) {
      xvn = *(const float4*)(x + (row0 + r) * DIM + C0 + 64 + q * 4);
      #pragma unroll
      for (int e = 0; e < NEXP; ++e)
        gwvn[e] = *(const float4*)(gw + (size_t)e * DIM + C0 + 64 + q * 4);
    }
    __builtin_amdgcn_sched_barrier(0);
    ushort4 s; s.x = f2bf(xv.x); s.y = f2bf(xv.y); s.z = f2bf(xv.z); s.w = f2bf(xv.w);
    *(ushort4*)(xaug + (row0 + r) * KAUG + C0 + q * 4) = s;
    #pragma unroll
    for (int e = 0; e < NEXP; ++e)
      ga[e] += xv.x * gwv[e].x + xv.y * gwv[e].y + xv.z * gwv[e].z + xv.w * gwv[e].w;
    {
      const int ch = q >> 1;
      const int by = r * 128 + ((ch ^ (r & 7)) * 16) + (q & 1) * 8;
      *(ushort4*)((char*)xb + by) = s;
    }
    if (c + 1 < 32) asm volatile("s_waitcnt vmcnt(14) lgkmcnt(0)" ::: "memory");
    else            asm volatile("s_waitcnt vmcnt(0) lgkmcnt(0)" ::: "memory");
    __builtin_amdgcn_sched_barrier(0);
    __builtin_amdgcn_s_barrier();

    const char* laP = (const char*)la[c & 1];
    const char* xbP = (const char*)xb;
    #pragma unroll
    for (int ks = 0; ks < 2; ++ks) {
      const int ra = lane & 15;
      const int pa = ((ks * 4 + (lane >> 4)) ^ (ra & 7)) * 16;
      bf16x8 avf = *(const bf16x8*)(xbP + ra * 128 + pa);
      const int rbA = (lane & 15) + 16 * nfA;
      const int rbB = (lane & 15) + 16 * nfB;
      bf16x8 bvA = *(const bf16x8*)(laP + rbA * 128 + (((ks * 4 + (lane >> 4)) ^ (rbA & 7)) * 16));
      bf16x8 bvB = *(const bf16x8*)(laP + rbB * 128 + (((ks * 4 + (lane >> 4)) ^ (rbB & 7)) * 16));
      acc[0] = __builtin_amdgcn_mfma_f32_16x16x32_bf16(avf, bvA, acc[0], 0, 0, 0);
      acc[1] = __builtin_amdgcn_mfma_f32_16x16x32_bf16(avf, bvB, acc[1], 0, 0, 0);
    }
    __builtin_amdgcn_s_barrier();
    __builtin_amdgcn_sched_barrier(0);
    xv = xvn;
    #pragma unroll
    for (int e = 0; e < NEXP; ++e) gwv[e] = gwvn[e];
  }

  #pragma unroll
  for (int e = 0; e < NEXP; ++e) {
    float v = ga[e];
    v += __shfl_xor(v, 1); v += __shfl_xor(v, 2);
    v += __shfl_xor(v, 4); v += __shfl_xor(v, 8);
    ga[e] = v + gb[e];
  }
  if (q == 0) {
    int e0 = 0; float m0 = ga[0];
    #pragma unroll
    for (int e = 1; e < NEXP; ++e) if (ga[e] > m0) { m0 = ga[e]; e0 = e; }
    int e1 = (e0 == 0) ? 1 : 0; float m1 = ga[e1];
    #pragma unroll
    for (int e = 0; e < NEXP; ++e) if (e != e0 && ga[e] > m1) { m1 = ga[e]; e1 = e; }
    float tt  = expf(m1 - m0);
    float inv = 1.f / (1.f + tt);
    float4 gg; gg.x = inv; gg.y = tt * inv;
    gg.z = __int_as_float(e0); gg.w = __int_as_float(e1);
    gates[r] = gg;
  }
  __syncthreads();

  #pragma unroll
  for (int nfl = 0; nfl < 2; ++nfl) {
    const int e = 2 * wave + nfl;
    const int n = e * 16 + (lane & 15);
    #pragma unroll
    for (int j = 0; j < 4; ++j) {
      const int m = (lane >> 4) * 4 + j;
      float4 gg = gates[m];
      const float g = (e == __float_as_int(gg.z)) ? gg.x
                    : ((e == __float_as_int(gg.w)) ? gg.y : 0.f);
      xaug[(row0 + m) * KAUG + DIM + n] = f2bf(acc[nfl][j] * g);
    }
  }
}

// ---- K4: round-8 structure, vmcnt(7) for a 1-op safety margin (r16).
// 256x256 tile, BK=64, 2-slot ring, 3-group MFMA interleave ----
__global__ __launch_bounds__(512, 2) void gemm256_pipe(
    const u16* __restrict__ A, int lda,
    const u16* __restrict__ Bm, int ldb,
    int Ksz, int grid_n,
    float* __restrict__ outF, int ldo, const float* __restrict__ bias)
{
  __shared__ __align__(16) u16 smem[65536];      // 128 KiB: A[2][32K] | B[2][32K]

  const int tid  = threadIdx.x;
  const int wave = tid >> 6;
  const int lane = tid & 63;

  int bid = blockIdx.x;
  const int nwg = gridDim.x;
  if ((nwg & 7) == 0) {                          // bijective XCD swizzle
    const int cpx = nwg >> 3;
    bid = (bid & 7) * cpx + (bid >> 3);
  }
  const int tm = bid / grid_n;
  const int tn = bid % grid_n;
  const size_t row0 = (size_t)tm * 256;
  const size_t col0 = (size_t)tn * 256;

  const int l3  = lane >> 3;
  const int sch = ((lane & 7) ^ l3) << 4;
  const char* aSrc = (const char*)(A  + (row0 + (size_t)(wave * 8 + l3)) * lda) + sch;
  const char* bSrc = (const char*)(Bm + (col0 + (size_t)(wave * 8 + l3)) * ldb) + sch;
  const size_t arst = (size_t)lda * 128;
  const size_t brst = (size_t)ldb * 128;
  char* ldsA = (char*)smem + wave * 1024;
  char* ldsB = (char*)smem + 65536 + wave * 1024;

  auto stage = [&](int tt) {
    const size_t ko = (size_t)tt * 128;
    const int    sb = (tt & 1) << 15;
    #pragma unroll
    for (int i = 0; i < 4; ++i)
      GLOAD(aSrc + ko + i * arst, ldsA + sb + i * 8192);
    #pragma unroll
    for (int i = 0; i < 4; ++i)
      GLOAD(bSrc + ko + i * brst, ldsB + sb + i * 8192);
  };

  const int wm = wave >> 2, wn = wave & 3;
  const int x0 = ((lane >> 4) ^ (lane & 7)) << 4;
  const int offA0 = wm * 16384 + (lane & 15) * 128 + x0;
  const int offB0 = wn * 8192  + (lane & 15) * 128 + x0;

  f32x4 acc[8][4] = {};

  const int nk = Ksz / 64;                        // 34
  stage(0); stage(1);

  for (int t = 0; t < nk; ++t) {
    if (t + 1 < nk) asm volatile("s_waitcnt vmcnt(7)" ::: "memory");
    else            asm volatile("s_waitcnt vmcnt(0)" ::: "memory");
    __builtin_amdgcn_s_barrier();
    __builtin_amdgcn_sched_barrier(0);

    const char* sa = (const char*)smem + ((t & 1) << 15);
    const char* sb = (const char*)smem + 65536 + ((t & 1) << 15);

    bf16x8 av0[8], bv0[4], av1[8], bv1[4];
    // ks0 reads
    #pragma unroll
    for (int mf = 0; mf < 8; ++mf) av0[mf] = *(const bf16x8*)(sa + offA0 + mf * 2048);
    #pragma unroll
    for (int nf = 0; nf < 4; ++nf) bv0[nf] = *(const bf16x8*)(sb + offB0 + nf * 2048);
    // group 1: ks0 x nf0-1 (16 MFMA)
    __builtin_amdgcn_s_setprio(1);
    #pragma unroll
    for (int mf = 0; mf < 8; ++mf)
      #pragma unroll
      for (int nf = 0; nf < 2; ++nf)
        acc[mf][nf] = __builtin_amdgcn_mfma_f32_16x16x32_bf16(
            av0[mf], bv0[nf], acc[mf][nf], 0, 0, 0);
    __builtin_amdgcn_s_setprio(0);
    // ks1 reads — issue overlaps group-2 MFMA
    #pragma unroll
    for (int mf = 0; mf < 8; ++mf) av1[mf] = *(const bf16x8*)(sa + (offA0 ^ 64) + mf * 2048);
    #pragma unroll
    for (int nf = 0; nf < 4; ++nf) bv1[nf] = *(const bf16x8*)(sb + (offB0 ^ 64) + nf * 2048);
    // group 2: ks0 x nf2-3 (16 MFMA)
    __builtin_amdgcn_s_setprio(1);
    #pragma unroll
    for (int mf = 0; mf < 8; ++mf)
      #pragma unroll
      for (int nf = 2; nf < 4; ++nf)
        acc[mf][nf] = __builtin_amdgcn_mfma_f32_16x16x32_bf16(
            av0[mf], bv0[nf], acc[mf][nf], 0, 0, 0);
    __builtin_amdgcn_s_setprio(0);
    // slot free after all reads complete in every wave
    asm volatile("s_waitcnt lgkmcnt(0)" ::: "memory");
    __builtin_amdgcn_s_barrier();
    __builtin_amdgcn_sched_barrier(0);
    if (t + 2 < nk) stage(t + 2);
    // group 3: ks1 x all nf (32 MFMA) — covers staging
    __builtin_amdgcn_s_setprio(1);
    #pragma unroll
    for (int mf = 0; mf < 8; ++mf)
      #pragma unroll
      for (int nf = 0; nf < 4; ++nf)
        acc[mf][nf] = __builtin_amdgcn_mfma_f32_16x16x32_bf16(
            av1[mf], bv1[nf], acc[mf][nf], 0, 0, 0);
    __builtin_amdgcn_s_setprio(0);
  }

  #pragma unroll
  for (int nf = 0; nf < 4; ++nf) {
    const size_t c = col0 + wn * 64 + nf * 16 + (lane & 15);
    const float bvv = bias[c];
    #pragma unroll
    for (int mf = 0; mf < 8; ++mf) {
      const size_t rb = row0 + wm * 128 + mf * 16 + ((lane >> 4) << 2);
      #pragma unroll
      for (int j = 0; j < 4; ++j)
        outF[(rb + j) * (size_t)ldo + c] = acc[mf][nf][j] + bvv;
    }
  }
}

extern "C" void kernel_launch(void* const* d_in, const int* in_sizes, int n_in,
                              void* d_out, int out_size, void* d_ws, size_t ws_size,
                              hipStream_t stream) {
  const float* x  = (const float*)d_in[0];
  const float* W  = (const float*)d_in[1];
  const float* b  = (const float*)d_in[2];
  const float* lA = (const float*)d_in[3];
  const float* lB = (const float*)d_in[4];
  const float* gw = (const float*)d_in[5];
  const float* gb = (const float*)d_in[6];
  float* out = (float*)d_out;

  u16* xaug = (u16*)d_ws;                          // [8192][2176]
  u16* waug = xaug + (size_t)N_ROWS * KAUG;        // [2048][2176]
  u16* ab   = waug + (size_t)OUTD * KAUG;          // [128][2048]

  hipLaunchKernelGGL(k2a_lora, dim3(ZCOLS), dim3(256), 0, stream, lA, ab);
  hipLaunchKernelGGL(kfw_fused, dim3(512 + OUTD), dim3(256), 0, stream,
                     x, gw, gb, ab, xaug, W, lB, waug);
  hipLaunchKernelGGL(gemm256_pipe,
                     dim3((N_ROWS / 256) * (OUTD / 256)), dim3(512), 0, stream,
                     xaug, KAUG, waug, KAUG, KAUG, OUTD / 256,
                     out, OUTD, b);
}